// Round 3
// baseline (187.776 us; speedup 1.0000x reference)
//
#include <hip/hip_runtime.h>
#include <type_traits>
#include <utility>

#define CDIM   45
#define LMAXX  8
#define WAVES_PB 8
#define VOXPB  64
#define VDIM   64
#define VPT    (VDIM / WAVES_PB)   // 8 vectors per wave
#define BLOCK  (WAVES_PB * 64)     // 512 threads

// ---------------- compile-time SH constant tables ----------------
constexpr double PI_D = 3.14159265358979323846;

constexpr double dfactd(int n){ double o=1.0; for(int k=n;k>1;k-=2) o*=k; return o; }
constexpr double factd (int n){ double o=1.0; for(int k=2;k<=n;++k) o*=k; return o; }
constexpr double csqrtd(double x){
  if(x<=0.0) return 0.0;
  double g = x>1.0 ? x : 1.0;
  for(int i=0;i<200;++i) g = 0.5*(g + x/g);
  return g;
}

struct SHTab {
  float c1[LMAXX+1][LMAXX+1];  // (2l-1)/(l-m)
  float c2[LMAXX+1][LMAXX+1];  // (l+m-1)/(l-m)
  float qmm[LMAXX+1];          // (-1)^m (2m-1)!!
  float qnx[LMAXX+1];          // (2m+1)*qmm
  float CP [LMAXX+1][LMAXX+1]; // combined: m==0 ? K : sgn*sqrt2*K
};

constexpr SHTab makeTab(){
  SHTab t{};
  for(int m=0;m<=LMAXX;++m){
    double q = ((m&1)?-1.0:1.0)*dfactd(2*m-1);
    t.qmm[m]=(float)q;
    t.qnx[m]=(float)((2.0*m+1.0)*q);
    for(int l=m+2;l<=LMAXX;++l){
      t.c1[m][l]=(float)((2.0*l-1.0)/(double)(l-m));
      t.c2[m][l]=(float)((double)(l+m-1)/(double)(l-m));
    }
    for(int l=m;l<=LMAXX;++l){
      double K = csqrtd((2.0*l+1.0)/(4.0*PI_D)*factd(l-m)/factd(l+m));
      double v = (m==0)? K : (((m&1)?-1.0:1.0)*csqrtd(2.0)*K);
      t.CP[m][l]=(float)v;
    }
  }
  return t;
}
constexpr SHTab SHT = makeTab();

// block offsets for even l: l=0,2,4,6,8 -> 0,1,6,15,28 ; idx(l,m)=offL(l)+l+m
constexpr int offL(int l){ return l==0?0 : (l==2?1 : (l==4?6 : (l==6?15 : 28))); }

// compile-time unroller (indices are constants -> acc[] stays in registers)
template<int N, typename F>
__device__ __forceinline__ void cunroll(F&& f){
  if constexpr (N > 0){
    cunroll<N-1>(f);
    f(std::integral_constant<int, N-1>{});
  }
}

// ---------------- kernel ----------------
// 512 threads = 8 waves; each wave: 64 voxels (1/lane) x 8 vectors.
// 4096 waves total = 4 waves/SIMD IF vgpr<=128 (hence launch_bounds(512,4)).
__global__ __launch_bounds__(BLOCK, 4)
void fodf_reorient_kernel(const float* __restrict__ image,
                          const float* __restrict__ affine,
                          const float* __restrict__ psf,
                          const float* __restrict__ Mp,
                          float* __restrict__ out,
                          int Nvox)
{
  __shared__ float red[VOXPB][CDIM+1];   // 64 x 46 floats = 11.8 KiB, stride 46 -> 2-way alias (free)

  const int tid  = threadIdx.x;
  const int lane = tid & 63;
  const int wvi  = __builtin_amdgcn_readfirstlane(tid >> 6); // wave id 0..7 (uniform)
  const int voxBase = blockIdx.x * VOXPB;
  int vox = voxBase + lane;
  if (vox >= Nvox) vox = Nvox - 1;       // clamp; stores are guarded below

  // zero the reduction buffer, then one barrier before any ds_add
  #pragma unroll 1
  for (int i = tid; i < VOXPB*(CDIM+1); i += BLOCK) (&red[0][0])[i] = 0.0f;
  __syncthreads();

  // ---- per-voxel loads (one lane = one voxel) ----
  float img[CDIM];
  {
    const float* ip = image + (size_t)vox * CDIM;
    #pragma unroll
    for(int c=0;c<CDIM;++c) img[c] = ip[c];
  }
  float a[9];
  {
    const float* ap = affine + (size_t)vox * 9;
    #pragma unroll
    for(int i=0;i<9;++i) a[i] = ap[i];
  }

  // ---- 3x3 inverse via adjugate ----
  const float det = a[0]*(a[4]*a[8]-a[5]*a[7])
                  - a[1]*(a[3]*a[8]-a[5]*a[6])
                  + a[2]*(a[3]*a[7]-a[4]*a[6]);
  const float rdet = 1.0f/det;
  const float i00 =  (a[4]*a[8]-a[5]*a[7])*rdet;
  const float i01 = -(a[1]*a[8]-a[2]*a[7])*rdet;
  const float i02 =  (a[1]*a[5]-a[2]*a[4])*rdet;
  const float i10 = -(a[3]*a[8]-a[5]*a[6])*rdet;
  const float i11 =  (a[0]*a[8]-a[2]*a[6])*rdet;
  const float i12 = -(a[0]*a[5]-a[2]*a[3])*rdet;
  const float i20 =  (a[3]*a[7]-a[4]*a[6])*rdet;
  const float i21 = -(a[0]*a[7]-a[1]*a[6])*rdet;
  const float i22 =  (a[0]*a[4]-a[1]*a[3])*rdet;

  float acc[CDIM];
  #pragma unroll
  for(int c=0;c<CDIM;++c) acc[c]=0.0f;

  // ---- this wave's 8 PSF vectors (v wave-uniform -> SGPR broadcast loads) ----
  const int vbase = wvi * VPT;
  #pragma unroll 1
  for(int k=0;k<VPT;++k){
    const int v = vbase + k;
    const float sxv = psf[3*v+0];
    const float syv = psf[3*v+1];
    const float szv = psf[3*v+2];

    // vi_hat = A^{-1} @ psf[v]
    const float hx = fmaf(i00,sxv, fmaf(i01,syv, i02*szv));
    const float hy = fmaf(i10,sxv, fmaf(i11,syv, i12*szv));
    const float hz = fmaf(i20,sxv, fmaf(i21,syv, i22*szv));

    const float r2  = fmaf(hx,hx, fmaf(hy,hy, hz*hz));
    const float rin = rsqrtf(r2 + 1e-12f);        // hw rsqrt, ~1e-6 rel: fine vs 1.6e-2 tol
    // xyz -> yzx permute, then normalize
    const float px = hy*rin;
    const float py = hz*rin;
    const float pz = hx*rin;

    // w[v] = dot(M_p[v,:], img) — wave-uniform row (SGPR operands)
    const float* Mrow = Mp + v*CDIM;
    float w0=0.f,w1=0.f,w2=0.f,w3=0.f;
    #pragma unroll
    for(int c=0;c<44;c+=4){
      w0 = fmaf(Mrow[c+0], img[c+0], w0);
      w1 = fmaf(Mrow[c+1], img[c+1], w1);
      w2 = fmaf(Mrow[c+2], img[c+2], w2);
      w3 = fmaf(Mrow[c+3], img[c+3], w3);
    }
    w0 = fmaf(Mrow[44], img[44], w0);
    const float wval = (w0+w1)+(w2+w3);
    // mod*w = |vi_hat|*det(A)*w ;  sqrt(r2) == r2*rsqrt(r2)
    const float wmod = r2 * rin * det * wval;

    // rolling A/B recurrence fused with per-|m| Q chains (keeps live set small)
    float Ap = 1.0f, Bp = 0.0f;                    // A_0, B_0
    cunroll<LMAXX+1>([&](auto AMc){
      constexpr int AM = decltype(AMc)::value;
      float Acur, Bcur;
      if constexpr (AM==0){ Acur = 1.0f; Bcur = 0.0f; }
      else {
        Acur = fmaf(px, Ap, -(py*Bp));
        Bcur = fmaf(px, Bp,  (py*Ap));
      }
      const float fa = (AM==0) ? wmod : wmod*Acur;
      const float fb = wmod*Bcur;                  // dead for AM==0 (DCE)
      float qp2 = SHT.qmm[AM];                     // Q[AM][AM]
      float qp1 = SHT.qnx[AM]*pz;                  // Q[AM+1][AM] (dead for AM==8)

      if constexpr ((AM&1)==0){                    // l = AM (even): emit
        constexpr float C = SHT.CP[AM][AM];
        const float t = qp2 * C;
        if constexpr (AM==0){
          acc[0] = fmaf(t, wmod, acc[0]);
        } else {
          acc[offL(AM)+2*AM] = fmaf(t, fa, acc[offL(AM)+2*AM]);
          acc[offL(AM)+0   ] = fmaf(t, fb, acc[offL(AM)+0   ]);
        }
      }
      if constexpr (AM<LMAXX && (((AM+1)&1)==0)){  // l = AM+1 even
        constexpr int L = AM+1;
        constexpr float C = SHT.CP[AM][L];
        const float t = qp1 * C;
        acc[offL(L)+L+AM] = fmaf(t, fa, acc[offL(L)+L+AM]);
        acc[offL(L)+L-AM] = fmaf(t, fb, acc[offL(L)+L-AM]);
      }

      constexpr int CNT = (LMAXX-AM-1) > 0 ? (LMAXX-AM-1) : 0;  // l = AM+2..8
      cunroll<CNT>([&](auto Lc){
        constexpr int L = AM + 2 + decltype(Lc)::value;
        constexpr float C1 = SHT.c1[AM][L];
        constexpr float C2 = SHT.c2[AM][L];
        const float q = fmaf(C1*pz, qp1, -(C2*qp2));
        qp2 = qp1; qp1 = q;
        if constexpr ((L&1)==0){
          constexpr float C = SHT.CP[AM][L];
          const float t = q * C;
          if constexpr (AM==0){
            acc[offL(L)+L] = fmaf(t, wmod, acc[offL(L)+L]);
          } else {
            acc[offL(L)+L+AM] = fmaf(t, fa, acc[offL(L)+L+AM]);
            acc[offL(L)+L-AM] = fmaf(t, fb, acc[offL(L)+L-AM]);
          }
        }
      });

      Ap = Acur; Bp = Bcur;
    });
  }

  // ---- cross-wave reduction: LDS float atomics (ds_add_f32), stride-46 rows ----
  #pragma unroll
  for(int c=0;c<CDIM;++c) atomicAdd(&red[lane][c], acc[c]);
  __syncthreads();

  // ---- gather + coalesced store ----
  const int total = VOXPB * CDIM;
  #pragma unroll 1
  for(int i = tid; i < total; i += BLOCK){
    const int vx = i / CDIM;                       // magic-mul div by 45
    const int c  = i - vx*CDIM;
    if (voxBase + vx < Nvox)
      out[(size_t)voxBase*CDIM + i] = red[vx][c];
  }
}

// ---------------- launch ----------------
extern "C" void kernel_launch(void* const* d_in, const int* in_sizes, int n_in,
                              void* d_out, int out_size, void* d_ws, size_t ws_size,
                              hipStream_t stream)
{
  const float* image  = (const float*)d_in[0];
  const float* affine = (const float*)d_in[1];
  const float* psf    = (const float*)d_in[2];
  const float* Mp     = (const float*)d_in[3];
  float* out = (float*)d_out;

  const int Nvox = in_sizes[0] / CDIM;
  const int blocks = (Nvox + VOXPB - 1) / VOXPB;

  hipLaunchKernelGGL(fodf_reorient_kernel, dim3(blocks), dim3(BLOCK), 0, stream,
                     image, affine, psf, Mp, out, Nvox);
}

// Round 4
// 140.264 us; speedup vs baseline: 1.3387x; 1.3387x over previous
//
#include <hip/hip_runtime.h>
#include <type_traits>
#include <utility>

#define CDIM   45
#define LMAXX  8
#define VOXPB  64
#define VDIM   64

// ---------------- compile-time SH constant tables ----------------
constexpr double PI_D = 3.14159265358979323846;

constexpr double dfactd(int n){ double o=1.0; for(int k=n;k>1;k-=2) o*=k; return o; }
constexpr double factd (int n){ double o=1.0; for(int k=2;k<=n;++k) o*=k; return o; }
constexpr double csqrtd(double x){
  if(x<=0.0) return 0.0;
  double g = x>1.0 ? x : 1.0;
  for(int i=0;i<200;++i) g = 0.5*(g + x/g);
  return g;
}

struct SHTab {
  float c1[LMAXX+1][LMAXX+1];  // (2l-1)/(l-m)
  float c2[LMAXX+1][LMAXX+1];  // (l+m-1)/(l-m)
  float qmm[LMAXX+1];          // (-1)^m (2m-1)!!
  float qnx[LMAXX+1];          // (2m+1)*qmm
  float CP [LMAXX+1][LMAXX+1]; // combined: m==0 ? K : sgn*sqrt2*K
};

constexpr SHTab makeTab(){
  SHTab t{};
  for(int m=0;m<=LMAXX;++m){
    double q = ((m&1)?-1.0:1.0)*dfactd(2*m-1);
    t.qmm[m]=(float)q;
    t.qnx[m]=(float)((2.0*m+1.0)*q);
    for(int l=m+2;l<=LMAXX;++l){
      t.c1[m][l]=(float)((2.0*l-1.0)/(double)(l-m));
      t.c2[m][l]=(float)((double)(l+m-1)/(double)(l-m));
    }
    for(int l=m;l<=LMAXX;++l){
      double K = csqrtd((2.0*l+1.0)/(4.0*PI_D)*factd(l-m)/factd(l+m));
      double v = (m==0)? K : (((m&1)?-1.0:1.0)*csqrtd(2.0)*K);
      t.CP[m][l]=(float)v;
    }
  }
  return t;
}
constexpr SHTab SHT = makeTab();

// block offsets for even l: l=0,2,4,6,8 -> 0,1,6,15,28 ; idx(l,m)=offL(l)+l+m
constexpr int offL(int l){ return l==0?0 : (l==2?1 : (l==4?6 : (l==6?15 : 28))); }

template<int N, typename F>
__device__ __forceinline__ void cunroll(F&& f){
  if constexpr (N > 0){
    cunroll<N-1>(f);
    f(std::integral_constant<int, N-1>{});
  }
}

__device__ __forceinline__ void inv3x3(const float* __restrict__ ap,
                                       float& det,
                                       float& i00,float& i01,float& i02,
                                       float& i10,float& i11,float& i12,
                                       float& i20,float& i21,float& i22)
{
  float a0=ap[0],a1=ap[1],a2=ap[2],a3=ap[3],a4=ap[4],a5=ap[5],a6=ap[6],a7=ap[7],a8=ap[8];
  det = a0*(a4*a8-a5*a7) - a1*(a3*a8-a5*a6) + a2*(a3*a7-a4*a6);
  const float rdet = 1.0f/det;
  i00 =  (a4*a8-a5*a7)*rdet;
  i01 = -(a1*a8-a2*a7)*rdet;
  i02 =  (a1*a5-a2*a4)*rdet;
  i10 = -(a3*a8-a5*a6)*rdet;
  i11 =  (a0*a8-a2*a6)*rdet;
  i12 = -(a0*a5-a2*a3)*rdet;
  i20 =  (a3*a7-a4*a6)*rdet;
  i21 = -(a0*a7-a1*a6)*rdet;
  i22 =  (a0*a4-a1*a3)*rdet;
}

// ================= K1: per-(voxel,vector) modulated PSF weights =================
// 256 thr = 4 waves; lane = voxel, each wave 16 vectors. Live set ~70 VGPR (img[45]).
// wws[v*Nvox + n] = |A^{-1}v| * det(A) * dot(Mp[v,:], img[n,:])
__global__ __launch_bounds__(256)
void k1_weights(const float* __restrict__ image,
                const float* __restrict__ affine,
                const float* __restrict__ psf,
                const float* __restrict__ Mp,
                float* __restrict__ wws,
                int Nvox)
{
  const int lane = threadIdx.x & 63;
  const int wvi  = __builtin_amdgcn_readfirstlane(threadIdx.x >> 6); // 0..3
  const int voxBase = blockIdx.x * VOXPB;
  int vox = voxBase + lane;
  const bool valid = vox < Nvox;
  if (!valid) vox = Nvox - 1;

  float img[CDIM];
  {
    const float* ip = image + (size_t)vox * CDIM;
    #pragma unroll
    for(int c=0;c<CDIM;++c) img[c] = ip[c];
  }
  float det,i00,i01,i02,i10,i11,i12,i20,i21,i22;
  inv3x3(affine + (size_t)vox*9, det, i00,i01,i02,i10,i11,i12,i20,i21,i22);

  const int vbase = wvi * 16;
  #pragma unroll 1
  for(int k=0;k<16;++k){
    const int v = vbase + k;
    const float sxv = psf[3*v+0];
    const float syv = psf[3*v+1];
    const float szv = psf[3*v+2];
    const float hx = fmaf(i00,sxv, fmaf(i01,syv, i02*szv));
    const float hy = fmaf(i10,sxv, fmaf(i11,syv, i12*szv));
    const float hz = fmaf(i20,sxv, fmaf(i21,syv, i22*szv));
    const float r2  = fmaf(hx,hx, fmaf(hy,hy, hz*hz));
    const float rin = rsqrtf(r2 + 1e-12f);

    const float* Mrow = Mp + v*CDIM;                 // wave-uniform -> s_loads
    float w0=0.f,w1=0.f,w2=0.f,w3=0.f;
    #pragma unroll
    for(int c=0;c<44;c+=4){
      w0 = fmaf(Mrow[c+0], img[c+0], w0);
      w1 = fmaf(Mrow[c+1], img[c+1], w1);
      w2 = fmaf(Mrow[c+2], img[c+2], w2);
      w3 = fmaf(Mrow[c+3], img[c+3], w3);
    }
    w0 = fmaf(Mrow[44], img[44], w0);
    const float wval = (w0+w1)+(w2+w3);
    if (valid)
      wws[(size_t)v*Nvox + vox] = r2*rin*det*wval;   // sqrt(r2)=r2*rsqrt(r2)
  }
}

// ================= K2: SH evaluation + accumulate =================
// 512 thr = 8 waves; lane = voxel, each wave 8 vectors. No img[] -> ~100 VGPR.
// launch_bounds(512,2): min 2 blocks/CU (CUDA semantics, per round-3 evidence)
// => 16 waves/CU = 4 waves/SIMD => VGPR cap 128.
__global__ __launch_bounds__(512, 2)
void k2_sh(const float* __restrict__ affine,
           const float* __restrict__ psf,
           const float* __restrict__ wws,
           float* __restrict__ out,
           int Nvox)
{
  __shared__ float red[VOXPB*CDIM];   // stride 45: gcd(13,32)=1 -> 2-way alias (free)

  const int tid  = threadIdx.x;
  const int lane = tid & 63;
  const int wvi  = __builtin_amdgcn_readfirstlane(tid >> 6); // 0..7
  const int voxBase = blockIdx.x * VOXPB;
  int vox = voxBase + lane;
  if (vox >= Nvox) vox = Nvox - 1;

  #pragma unroll 1
  for (int i = tid; i < VOXPB*CDIM; i += 512) red[i] = 0.0f;
  __syncthreads();

  const int vbase = wvi * 8;

  // prefetch this wave's 8 wmod values (coalesced, independent)
  float wpre[8];
  #pragma unroll
  for(int k=0;k<8;++k) wpre[k] = wws[(size_t)(vbase+k)*Nvox + vox];

  float det,i00,i01,i02,i10,i11,i12,i20,i21,i22;
  inv3x3(affine + (size_t)vox*9, det, i00,i01,i02,i10,i11,i12,i20,i21,i22);

  float acc[CDIM];
  #pragma unroll
  for(int c=0;c<CDIM;++c) acc[c]=0.0f;

  #pragma unroll 1
  for(int k=0;k<8;++k){
    const int v = vbase + k;
    const float sxv = psf[3*v+0];
    const float syv = psf[3*v+1];
    const float szv = psf[3*v+2];
    const float hx = fmaf(i00,sxv, fmaf(i01,syv, i02*szv));
    const float hy = fmaf(i10,sxv, fmaf(i11,syv, i12*szv));
    const float hz = fmaf(i20,sxv, fmaf(i21,syv, i22*szv));
    const float r2  = fmaf(hx,hx, fmaf(hy,hy, hz*hz));
    const float rin = rsqrtf(r2 + 1e-12f);
    // xyz -> yzx permute, then normalize
    const float px = hy*rin;
    const float py = hz*rin;
    const float pz = hx*rin;

    const float wmod = wpre[k];

    // rolling A/B recurrence fused with per-|m| Q chains
    float Ap = 1.0f, Bp = 0.0f;
    cunroll<LMAXX+1>([&](auto AMc){
      constexpr int AM = decltype(AMc)::value;
      float Acur, Bcur;
      if constexpr (AM==0){ Acur = 1.0f; Bcur = 0.0f; }
      else {
        Acur = fmaf(px, Ap, -(py*Bp));
        Bcur = fmaf(px, Bp,  (py*Ap));
      }
      const float fa = (AM==0) ? wmod : wmod*Acur;
      const float fb = wmod*Bcur;
      float qp2 = SHT.qmm[AM];
      float qp1 = SHT.qnx[AM]*pz;

      if constexpr ((AM&1)==0){
        constexpr float C = SHT.CP[AM][AM];
        const float t = qp2 * C;
        if constexpr (AM==0){
          acc[0] = fmaf(t, wmod, acc[0]);
        } else {
          acc[offL(AM)+2*AM] = fmaf(t, fa, acc[offL(AM)+2*AM]);
          acc[offL(AM)+0   ] = fmaf(t, fb, acc[offL(AM)+0   ]);
        }
      }
      if constexpr (AM<LMAXX && (((AM+1)&1)==0)){
        constexpr int L = AM+1;
        constexpr float C = SHT.CP[AM][L];
        const float t = qp1 * C;
        acc[offL(L)+L+AM] = fmaf(t, fa, acc[offL(L)+L+AM]);
        acc[offL(L)+L-AM] = fmaf(t, fb, acc[offL(L)+L-AM]);
      }

      constexpr int CNT = (LMAXX-AM-1) > 0 ? (LMAXX-AM-1) : 0;
      cunroll<CNT>([&](auto Lc){
        constexpr int L = AM + 2 + decltype(Lc)::value;
        constexpr float C1 = SHT.c1[AM][L];
        constexpr float C2 = SHT.c2[AM][L];
        const float q = fmaf(C1*pz, qp1, -(C2*qp2));
        qp2 = qp1; qp1 = q;
        if constexpr ((L&1)==0){
          constexpr float C = SHT.CP[AM][L];
          const float t = q * C;
          if constexpr (AM==0){
            acc[offL(L)+L] = fmaf(t, wmod, acc[offL(L)+L]);
          } else {
            acc[offL(L)+L+AM] = fmaf(t, fa, acc[offL(L)+L+AM]);
            acc[offL(L)+L-AM] = fmaf(t, fb, acc[offL(L)+L-AM]);
          }
        }
      });

      Ap = Acur; Bp = Bcur;
    });
  }

  // cross-wave reduction: LDS float atomics (ds_add), linear stride-45 rows
  #pragma unroll
  for(int c=0;c<CDIM;++c) atomicAdd(&red[lane*CDIM + c], acc[c]);
  __syncthreads();

  // linear, coalesced store
  #pragma unroll 1
  for(int i = tid; i < VOXPB*CDIM; i += 512){
    const int vx = i / CDIM;
    if (voxBase + vx < Nvox)
      out[(size_t)voxBase*CDIM + i] = red[i];
  }
}

// ---------------- launch ----------------
extern "C" void kernel_launch(void* const* d_in, const int* in_sizes, int n_in,
                              void* d_out, int out_size, void* d_ws, size_t ws_size,
                              hipStream_t stream)
{
  const float* image  = (const float*)d_in[0];
  const float* affine = (const float*)d_in[1];
  const float* psf    = (const float*)d_in[2];
  const float* Mp     = (const float*)d_in[3];
  float* out = (float*)d_out;
  float* wws = (float*)d_ws;                 // 64 * Nvox floats = 8 MB << ws_size

  const int Nvox = in_sizes[0] / CDIM;
  const int blocks = (Nvox + VOXPB - 1) / VOXPB;

  hipLaunchKernelGGL(k1_weights, dim3(blocks), dim3(256), 0, stream,
                     image, affine, psf, Mp, wws, Nvox);
  hipLaunchKernelGGL(k2_sh, dim3(blocks), dim3(512), 0, stream,
                     affine, psf, wws, out, Nvox);
}